// Round 1
// baseline (5237.776 us; speedup 1.0000x reference)
//
#include <hip/hip_runtime.h>
#include <cstdint>
#include <cstddef>

// Problem constants (from reference): T,N,E,P,D,F = 24,10000,320000,20000,64,32
#define T_ 24
#define N_ 10000
#define E_ 320000
#define P_ 20000
#define D_ 64
#define F_ 32
#define XS_ 34   // x last-dim stride (F+2)

constexpr int NB = 32;        // nodes per gconv block
constexpr int THREADS = 256;  // threads per gconv block (8 threads per node)

// ---------------------------------------------------------------- preprocessing

__global__ void deg_kernel(const int* __restrict__ src, const int* __restrict__ dst,
                           int* __restrict__ deg_out, int* __restrict__ deg_in) {
  int e = blockIdx.x * blockDim.x + threadIdx.x;
  if (e < E_) {
    atomicAdd(&deg_out[src[e]], 1);
    atomicAdd(&deg_in[dst[e]], 1);
  }
}

__global__ void norm_kernel(const int* __restrict__ deg_in, const int* __restrict__ deg_out,
                            float* __restrict__ in_norm, float* __restrict__ out_norm) {
  int n = blockIdx.x * blockDim.x + threadIdx.x;
  if (n < N_) {
    in_norm[n]  = 1.0f / sqrtf(fmaxf((float)deg_in[n], 1.0f));
    out_norm[n] = 1.0f / sqrtf(fmaxf((float)deg_out[n], 1.0f));
  }
}

// exclusive scan of in-degrees -> row_ptr (single block, 1024 threads)
__global__ __launch_bounds__(1024) void scan_kernel(const int* __restrict__ deg,
                                                    int* __restrict__ row_ptr) {
  __shared__ int buf[1024];
  __shared__ int carry;
  int tid = threadIdx.x;
  if (tid == 0) { carry = 0; row_ptr[0] = 0; }
  __syncthreads();
  for (int base = 0; base < N_; base += 1024) {
    int i = base + tid;
    int v = (i < N_) ? deg[i] : 0;
    buf[tid] = v;
    __syncthreads();
    for (int off = 1; off < 1024; off <<= 1) {
      int tv = (tid >= off) ? buf[tid - off] : 0;
      __syncthreads();
      buf[tid] += tv;
      __syncthreads();
    }
    if (i < N_) row_ptr[i + 1] = carry + buf[tid];
    __syncthreads();
    if (tid == 0) carry += buf[1023];
    __syncthreads();
  }
}

__global__ void fill_kernel(const int* __restrict__ src, const int* __restrict__ dst,
                            const int* __restrict__ row_ptr, int* __restrict__ fill,
                            int* __restrict__ col, float* __restrict__ coef,
                            const float* __restrict__ out_norm) {
  int e = blockIdx.x * blockDim.x + threadIdx.x;
  if (e < E_) {
    int n = dst[e];
    int pos = row_ptr[n] + atomicAdd(&fill[n], 1);
    int s = src[e];
    col[pos] = s;
    coef[pos] = out_norm[s];
  }
}

__global__ void dvec_kernel(const float* __restrict__ dis, const int* __restrict__ ti,
                            float* __restrict__ dvec) {
  int p = blockIdx.x * blockDim.x + threadIdx.x;
  if (p < P_) {
    int i0 = ti[p];
    int i1 = ti[P_ + p];
    dvec[p] = dis[(size_t)i0 * N_ + i1];
  }
}

// ---------------------------------------------------------------- fused gconv
// agg[n] = in_norm[n] * sum_{e in CSR(n)} coef[e] * input(col[e])
// out    = act(agg @ W + b)   with optional fused GRU epilogues.
// MODE: 1 = relu -> out
//       2 = sigmoid; o<D: hr[n,o] = sig*h[n,o]; o>=D: z[n,o-D] = sig
//       3 = hnew = tanh; h[n,o] = z[n,o]*h[n,o] + (1-z)*hnew   (in place)
// CONCAT: input component i<D from hA (stride D), i>=D from xB (stride XS_)
template<int DIN, int DOUT, int MODE, bool CONCAT>
__global__ __launch_bounds__(THREADS) void gconv_kernel(
    const float* __restrict__ hA, const float* __restrict__ xB,
    const int* __restrict__ row_ptr, const int* __restrict__ col,
    const float* __restrict__ coef, const float* __restrict__ in_norm,
    const float* __restrict__ W, const float* __restrict__ bias,
    float* __restrict__ out,
    const float* __restrict__ hprev, float* __restrict__ hdst,
    float* __restrict__ zbuf) {
  __shared__ float sW[DIN * DOUT];
  __shared__ float sAgg[NB][DIN];

  const int tid = threadIdx.x;
  for (int i = tid; i < DIN * DOUT; i += THREADS) sW[i] = W[i];

  const int node0 = blockIdx.x * NB;
  const int grp = tid >> 3;   // node within block
  const int lane = tid & 7;   // 8 threads per node
  const int n = node0 + grp;

  constexpr int KC = DIN / 8;
  float acc[KC];
#pragma unroll
  for (int k = 0; k < KC; ++k) acc[k] = 0.0f;

  if (n < N_) {
    int e0 = row_ptr[n], e1 = row_ptr[n + 1];
    for (int e = e0; e < e1; ++e) {
      int s = col[e];
      float c = coef[e];
#pragma unroll
      for (int k = 0; k < KC; ++k) {
        int comp = lane + k * 8;
        float v;
        if (CONCAT) {
          if (comp < D_) v = hA[(size_t)s * D_ + comp];
          else           v = xB[(size_t)s * XS_ + (comp - D_)];
        } else {
          v = hA[(size_t)s * DIN + comp];
        }
        acc[k] += c * v;
      }
    }
    float inn = in_norm[n];
#pragma unroll
    for (int k = 0; k < KC; ++k) sAgg[grp][lane + k * 8] = acc[k] * inn;
  }
  __syncthreads();

  // GEMM: (NB x DIN) @ (DIN x DOUT) + epilogue
  constexpr int OUT_PER = NB * DOUT / THREADS;
#pragma unroll
  for (int r = 0; r < OUT_PER; ++r) {
    int idx = r * THREADS + tid;
    int nl = idx / DOUT;
    int o = idx % DOUT;
    int n2 = node0 + nl;
    if (n2 < N_) {
      float a = bias[o];
#pragma unroll 8
      for (int i = 0; i < DIN; ++i) a += sAgg[nl][i] * sW[i * DOUT + o];
      if (MODE == 1) {
        out[(size_t)n2 * DOUT + o] = fmaxf(a, 0.0f);
      } else if (MODE == 2) {
        float sg = 1.0f / (1.0f + expf(-a));
        if (o < D_) hdst[(size_t)n2 * D_ + o] = sg * hprev[(size_t)n2 * D_ + o];
        else        zbuf[(size_t)n2 * D_ + (o - D_)] = sg;
      } else if (MODE == 3) {
        float hn = tanhf(a);
        float zz = zbuf[(size_t)n2 * D_ + o];
        hdst[(size_t)n2 * D_ + o] = zz * hprev[(size_t)n2 * D_ + o] + (1.0f - zz) * hn;
      }
    }
  }
}

// ---------------------------------------------------------------- prediction
__global__ void pred_kernel(const float* __restrict__ h, const int* __restrict__ ti,
                            const float* __restrict__ dvec, const float* __restrict__ pW,
                            const float* __restrict__ pb, float* __restrict__ out, int t) {
  int p = blockIdx.x * blockDim.x + threadIdx.x;
  if (p < P_) {
    int i0 = ti[p];
    int i1 = ti[P_ + p];
    float a = pb[0] + dvec[p] * pW[2 * D_];
    const float* h0 = h + (size_t)i0 * D_;
    const float* h1 = h + (size_t)i1 * D_;
#pragma unroll 8
    for (int d = 0; d < D_; ++d) a += h0[d] * pW[d] + h1[d] * pW[D_ + d];
    out[(size_t)p * T_ + t] = tanhf(a);
  }
}

// ---------------------------------------------------------------- launch

extern "C" void kernel_launch(void* const* d_in, const int* in_sizes, int n_in,
                              void* d_out, int out_size, void* d_ws, size_t ws_size,
                              hipStream_t stream) {
  const float* x      = (const float*)d_in[0];
  const float* dis    = (const float*)d_in[1];
  const int*   src    = (const int*)d_in[2];
  const int*   dst    = (const int*)d_in[3];
  const int*   ti     = (const int*)d_in[4];
  const float* ru_W1  = (const float*)d_in[5];
  const float* ru_b1  = (const float*)d_in[6];
  const float* ru_W2  = (const float*)d_in[7];
  const float* ru_b2  = (const float*)d_in[8];
  const float* ru_W3  = (const float*)d_in[9];
  const float* ru_b3  = (const float*)d_in[10];
  const float* rh_W1  = (const float*)d_in[11];
  const float* rh_b1  = (const float*)d_in[12];
  const float* rh_W2  = (const float*)d_in[13];
  const float* rh_b2  = (const float*)d_in[14];
  const float* rh_W3  = (const float*)d_in[15];
  const float* rh_b3  = (const float*)d_in[16];
  const float* pred_W = (const float*)d_in[17];
  const float* pred_b = (const float*)d_in[18];
  float* out = (float*)d_out;

  char* w = (char*)d_ws;
  auto alloc = [&](size_t bytes) -> void* {
    void* p = (void*)w;
    w += (bytes + 255) & ~(size_t)255;
    return p;
  };
  int*   row_ptr  = (int*)alloc((N_ + 1) * sizeof(int));
  int*   colv     = (int*)alloc(E_ * sizeof(int));
  float* coef     = (float*)alloc(E_ * sizeof(float));
  int*   deg_in   = (int*)alloc(N_ * sizeof(int));
  int*   deg_out  = (int*)alloc(N_ * sizeof(int));
  int*   fillc    = (int*)alloc(N_ * sizeof(int));
  float* in_norm  = (float*)alloc(N_ * sizeof(float));
  float* out_norm = (float*)alloc(N_ * sizeof(float));
  float* dvec     = (float*)alloc(P_ * sizeof(float));
  float* h        = (float*)alloc((size_t)N_ * D_ * sizeof(float));
  float* hr       = (float*)alloc((size_t)N_ * D_ * sizeof(float));
  float* z        = (float*)alloc((size_t)N_ * D_ * sizeof(float));
  float* u1       = (float*)alloc((size_t)N_ * D_ * sizeof(float));
  float* u2       = (float*)alloc((size_t)N_ * D_ * sizeof(float));

  hipMemsetAsync(deg_in, 0, N_ * sizeof(int), stream);
  hipMemsetAsync(deg_out, 0, N_ * sizeof(int), stream);
  hipMemsetAsync(fillc, 0, N_ * sizeof(int), stream);
  hipMemsetAsync(h, 0, (size_t)N_ * D_ * sizeof(float), stream);

  deg_kernel<<<(E_ + 255) / 256, 256, 0, stream>>>(src, dst, deg_out, deg_in);
  norm_kernel<<<(N_ + 255) / 256, 256, 0, stream>>>(deg_in, deg_out, in_norm, out_norm);
  scan_kernel<<<1, 1024, 0, stream>>>(deg_in, row_ptr);
  fill_kernel<<<(E_ + 255) / 256, 256, 0, stream>>>(src, dst, row_ptr, fillc, colv, coef, out_norm);
  dvec_kernel<<<(P_ + 255) / 256, 256, 0, stream>>>(dis, ti, dvec);

  const int GB = (N_ + NB - 1) / NB;
  const int PB = (P_ + 255) / 256;

  for (int t = 0; t < T_; ++t) {
    const float* xt = x + (size_t)t * N_ * XS_;
    // gnn1 (ru): concat [h | xt]
    gconv_kernel<96, 64, 1, true><<<GB, THREADS, 0, stream>>>(
        h, xt, row_ptr, colv, coef, in_norm, ru_W1, ru_b1, u1, nullptr, nullptr, nullptr);
    gconv_kernel<64, 64, 1, false><<<GB, THREADS, 0, stream>>>(
        u1, nullptr, row_ptr, colv, coef, in_norm, ru_W2, ru_b2, u2, nullptr, nullptr, nullptr);
    gconv_kernel<64, 128, 2, false><<<GB, THREADS, 0, stream>>>(
        u2, nullptr, row_ptr, colv, coef, in_norm, ru_W3, ru_b3, nullptr, h, hr, z);
    // gnn2 (rh): concat [h*r | xt]
    gconv_kernel<96, 64, 1, true><<<GB, THREADS, 0, stream>>>(
        hr, xt, row_ptr, colv, coef, in_norm, rh_W1, rh_b1, u1, nullptr, nullptr, nullptr);
    gconv_kernel<64, 64, 1, false><<<GB, THREADS, 0, stream>>>(
        u1, nullptr, row_ptr, colv, coef, in_norm, rh_W2, rh_b2, u2, nullptr, nullptr, nullptr);
    gconv_kernel<64, 64, 3, false><<<GB, THREADS, 0, stream>>>(
        u2, nullptr, row_ptr, colv, coef, in_norm, rh_W3, rh_b3, nullptr, h, h, z);
    // prediction for this timestep (hs[t] == h after update)
    pred_kernel<<<PB, 256, 0, stream>>>(h, ti, dvec, pred_W, pred_b, out, t);
  }
}

// Round 2
// 3212.432 us; speedup vs baseline: 1.6305x; 1.6305x over previous
//
#include <hip/hip_runtime.h>
#include <cstdint>
#include <cstddef>

// Problem constants: T,N,E,P,D,F = 24,10000,320000,20000,64,32
#define T_ 24
#define N_ 10000
#define E_ 320000
#define P_ 20000
#define D_ 64
#define F_ 32
#define XS_ 34   // x last-dim stride (F+2)

// ---------------------------------------------------------------- preprocessing

__global__ void deg_kernel(const int* __restrict__ src, const int* __restrict__ dst,
                           int* __restrict__ deg_out, int* __restrict__ deg_in) {
  int e = blockIdx.x * blockDim.x + threadIdx.x;
  if (e < E_) {
    atomicAdd(&deg_out[src[e]], 1);
    atomicAdd(&deg_in[dst[e]], 1);
  }
}

__global__ void norm_kernel(const int* __restrict__ deg_in, const int* __restrict__ deg_out,
                            float* __restrict__ in_norm, float* __restrict__ out_norm) {
  int n = blockIdx.x * blockDim.x + threadIdx.x;
  if (n < N_) {
    in_norm[n]  = 1.0f / sqrtf(fmaxf((float)deg_in[n], 1.0f));
    out_norm[n] = 1.0f / sqrtf(fmaxf((float)deg_out[n], 1.0f));
  }
}

// exclusive scan of in-degrees -> row_ptr (single block)
__global__ __launch_bounds__(1024) void scan_kernel(const int* __restrict__ deg,
                                                    int* __restrict__ row_ptr) {
  __shared__ int buf[1024];
  __shared__ int carry;
  int tid = threadIdx.x;
  if (tid == 0) { carry = 0; row_ptr[0] = 0; }
  __syncthreads();
  for (int base = 0; base < N_; base += 1024) {
    int i = base + tid;
    int v = (i < N_) ? deg[i] : 0;
    buf[tid] = v;
    __syncthreads();
    for (int off = 1; off < 1024; off <<= 1) {
      int tv = (tid >= off) ? buf[tid - off] : 0;
      __syncthreads();
      buf[tid] += tv;
      __syncthreads();
    }
    if (i < N_) row_ptr[i + 1] = carry + buf[tid];
    __syncthreads();
    if (tid == 0) carry += buf[1023];
    __syncthreads();
  }
}

__global__ void fill_kernel(const int* __restrict__ src, const int* __restrict__ dst,
                            const int* __restrict__ row_ptr, int* __restrict__ fill,
                            int* __restrict__ col) {
  int e = blockIdx.x * blockDim.x + threadIdx.x;
  if (e < E_) {
    int n = dst[e];
    int pos = row_ptr[n] + atomicAdd(&fill[n], 1);
    col[pos] = src[e];
  }
}

__global__ void dvec_kernel(const float* __restrict__ dis, const int* __restrict__ ti,
                            float* __restrict__ dvec) {
  int p = blockIdx.x * blockDim.x + threadIdx.x;
  if (p < P_) {
    int i0 = ti[p];
    int i1 = ti[P_ + p];
    dvec[p] = dis[(size_t)i0 * N_ + i1];
  }
}

// ---------------------------------------------------------------- pre-transform
// tdst[n] = (out_norm[n] * [hsrc[n] | xt[n]]) @ W   (96 -> 64, no bias)
__global__ __launch_bounds__(256) void pre_kernel(
    const float* __restrict__ hsrc, const float* __restrict__ xt,
    const float* __restrict__ out_norm, const float* __restrict__ W,
    float* __restrict__ tdst) {
  __shared__ float sIn[32][96];
  __shared__ float sW[96 * 64];
  const int tid = threadIdx.x;
  const int node0 = blockIdx.x * 32;

  { // stage W (96x64 = 24KB)
    const float4* Wv = (const float4*)W;
    float4* sWv = (float4*)sW;
    for (int i = tid; i < 96 * 64 / 4; i += 256) sWv[i] = Wv[i];
  }
  // stage scaled inputs
  for (int idx = tid; idx < 32 * 96; idx += 256) {
    int r = idx / 96, c = idx % 96;
    int n = node0 + r;
    float v = 0.0f;
    if (n < N_) {
      v = (c < 64) ? hsrc[(size_t)n * 64 + c] : xt[(size_t)n * XS_ + (c - 64)];
      v *= out_norm[n];
    }
    sIn[r][c] = v;
  }
  __syncthreads();

  const int o = tid & 63;
  const int q = tid >> 6;  // 0..3, 8 rows each
  float acc[8];
#pragma unroll
  for (int j = 0; j < 8; ++j) acc[j] = 0.0f;
#pragma unroll 4
  for (int i = 0; i < 96; ++i) {
    float w = sW[i * 64 + o];
#pragma unroll
    for (int j = 0; j < 8; ++j) acc[j] += sIn[q * 8 + j][i] * w;
  }
#pragma unroll
  for (int j = 0; j < 8; ++j) {
    int n = node0 + q * 8 + j;
    if (n < N_) tdst[(size_t)n * 64 + o] = acc[j];
  }
}

// ---------------------------------------------------------------- fused gather
// s[n] = sum_{e in CSR(n)} t[col[e]]   (t is pre-scaled by out_norm at producer)
// MODE 0: u = relu(in_norm*s + bias); out[n] = (out_norm[n]*u) @ W   (64->64)
// MODE 1: out[n][i] = out_norm[n] * relu(in_norm*s[i] + bias[i])     (no W)
// MODE 2: a = (in_norm*s) @ W + bias (64->128); sg=sigmoid(a);
//         o<64: hdst[n,o]=sg*hprev[n,o];  o>=64: zdst[n,o-64]=sg
// MODE 3: a = (in_norm*s) @ W + bias (64->64); hn=tanh(a);
//         hdst[n,o] = zsrc[n,o]*hprev[n,o] + (1-zsrc)*hn
template<int DOUT, int MODE>
__global__ __launch_bounds__(512) void gather_kernel(
    const float* __restrict__ t, const int* __restrict__ row_ptr,
    const int* __restrict__ col, const float* __restrict__ in_norm,
    const float* __restrict__ out_norm, const float* __restrict__ W,
    const float* __restrict__ bias, float* __restrict__ out,
    const float* __restrict__ hprev, float* __restrict__ hdst,
    const float* __restrict__ zsrc, float* __restrict__ zdst) {
  __shared__ float4 sAgg4[8][16];
  constexpr int WELEMS = (MODE == 1) ? 4 : (64 * DOUT);
  __shared__ float sW[WELEMS];

  const int tid = threadIdx.x;
  if constexpr (MODE != 1) {
    const float4* Wv = (const float4*)W;
    float4* sWv = (float4*)sW;
    for (int i = tid; i < WELEMS / 4; i += 512) sWv[i] = Wv[i];
  }

  const int wave = tid >> 6;
  const int lane = tid & 63;
  const int g = lane >> 4;    // edge slice 0..3
  const int sub = lane & 15;  // float4 index within row
  const int n = blockIdx.x * 8 + wave;

  float4 acc = make_float4(0.f, 0.f, 0.f, 0.f);
  if (n < N_) {
    int e0 = row_ptr[n], e1 = row_ptr[n + 1];
    int e = e0 + g;
    int snext = (e < e1) ? col[e] : 0;
    for (; e < e1; e += 4) {
      int s = snext;
      int en = e + 4;
      snext = (en < e1) ? col[en] : 0;
      float4 v = ((const float4*)(t + (size_t)s * 64))[sub];
      acc.x += v.x; acc.y += v.y; acc.z += v.z; acc.w += v.w;
    }
  }
  // reduce across the 4 slices (bits 4 and 5 of lane)
#pragma unroll
  for (int off = 16; off < 64; off <<= 1) {
    acc.x += __shfl_xor(acc.x, off);
    acc.y += __shfl_xor(acc.y, off);
    acc.z += __shfl_xor(acc.z, off);
    acc.w += __shfl_xor(acc.w, off);
  }

  if (n < N_ && g == 0) {
    float inn = in_norm[n];
    float4 val;
    if constexpr (MODE == 0 || MODE == 1) {
      float on = out_norm[n];
      float4 b4 = ((const float4*)bias)[sub];
      val.x = on * fmaxf(inn * acc.x + b4.x, 0.0f);
      val.y = on * fmaxf(inn * acc.y + b4.y, 0.0f);
      val.z = on * fmaxf(inn * acc.z + b4.z, 0.0f);
      val.w = on * fmaxf(inn * acc.w + b4.w, 0.0f);
    } else {
      val.x = inn * acc.x; val.y = inn * acc.y;
      val.z = inn * acc.z; val.w = inn * acc.w;
    }
    if constexpr (MODE == 1) {
      ((float4*)(out + (size_t)n * 64))[sub] = val;
    } else {
      sAgg4[wave][sub] = val;
    }
  }
  if constexpr (MODE == 1) return;
  __syncthreads();

  if (n >= N_) return;
  const float* sAgg = (const float*)&sAgg4[wave][0];
  const int o = lane;

  if constexpr (MODE == 0) {
    float a = 0.0f;
#pragma unroll 8
    for (int i = 0; i < 64; ++i) a += sAgg[i] * sW[i * 64 + o];
    out[(size_t)n * 64 + o] = a;
  } else if constexpr (MODE == 2) {
    float a0 = bias[o], a1 = bias[o + 64];
#pragma unroll 8
    for (int i = 0; i < 64; ++i) {
      float ai = sAgg[i];
      a0 += ai * sW[i * 128 + o];
      a1 += ai * sW[i * 128 + o + 64];
    }
    float r = 1.0f / (1.0f + expf(-a0));
    float z = 1.0f / (1.0f + expf(-a1));
    hdst[(size_t)n * 64 + o] = r * hprev[(size_t)n * 64 + o];
    zdst[(size_t)n * 64 + o] = z;
  } else {  // MODE 3
    float a = bias[o];
#pragma unroll 8
    for (int i = 0; i < 64; ++i) a += sAgg[i] * sW[i * 64 + o];
    float hn = tanhf(a);
    float zz = zsrc[(size_t)n * 64 + o];
    float hp = hprev[(size_t)n * 64 + o];
    hdst[(size_t)n * 64 + o] = zz * hp + (1.0f - zz) * hn;
  }
}

// ---------------------------------------------------------------- prediction
// 16 lanes per pair, coalesced row reads + shuffle reduce
__global__ __launch_bounds__(256) void pred_kernel(
    const float* __restrict__ h, const int* __restrict__ ti,
    const float* __restrict__ dvec, const float* __restrict__ pW,
    const float* __restrict__ pb, float* __restrict__ out, int t) {
  const int tid = threadIdx.x;
  const int lane = tid & 63;
  const int wave = tid >> 6;
  const int g2 = lane >> 4;   // pair within wave
  const int sub = lane & 15;  // float4 slot
  const int p = blockIdx.x * 16 + wave * 4 + g2;
  if (p >= P_) return;

  int i0 = ti[p];
  int i1 = ti[P_ + p];
  float4 a0 = ((const float4*)(h + (size_t)i0 * 64))[sub];
  float4 w0 = ((const float4*)pW)[sub];
  float4 a1 = ((const float4*)(h + (size_t)i1 * 64))[sub];
  float4 w1 = ((const float4*)(pW + 64))[sub];
  float part = a0.x * w0.x + a0.y * w0.y + a0.z * w0.z + a0.w * w0.w
             + a1.x * w1.x + a1.y * w1.y + a1.z * w1.z + a1.w * w1.w;
#pragma unroll
  for (int off = 1; off < 16; off <<= 1) part += __shfl_xor(part, off);
  if (sub == 0) {
    float a = part + pb[0] + dvec[p] * pW[128];
    out[(size_t)p * T_ + t] = tanhf(a);
  }
}

// ---------------------------------------------------------------- launch

extern "C" void kernel_launch(void* const* d_in, const int* in_sizes, int n_in,
                              void* d_out, int out_size, void* d_ws, size_t ws_size,
                              hipStream_t stream) {
  const float* x      = (const float*)d_in[0];
  const float* dis    = (const float*)d_in[1];
  const int*   src    = (const int*)d_in[2];
  const int*   dst    = (const int*)d_in[3];
  const int*   ti     = (const int*)d_in[4];
  const float* ru_W1  = (const float*)d_in[5];
  const float* ru_b1  = (const float*)d_in[6];
  const float* ru_W2  = (const float*)d_in[7];
  const float* ru_b2  = (const float*)d_in[8];
  const float* ru_W3  = (const float*)d_in[9];
  const float* ru_b3  = (const float*)d_in[10];
  const float* rh_W1  = (const float*)d_in[11];
  const float* rh_b1  = (const float*)d_in[12];
  const float* rh_W2  = (const float*)d_in[13];
  const float* rh_b2  = (const float*)d_in[14];
  const float* rh_W3  = (const float*)d_in[15];
  const float* rh_b3  = (const float*)d_in[16];
  const float* pred_W = (const float*)d_in[17];
  const float* pred_b = (const float*)d_in[18];
  float* out = (float*)d_out;

  char* w = (char*)d_ws;
  auto alloc = [&](size_t bytes) -> void* {
    void* p = (void*)w;
    w += (bytes + 255) & ~(size_t)255;
    return p;
  };
  int*   row_ptr  = (int*)alloc((N_ + 1) * sizeof(int));
  int*   colv     = (int*)alloc(E_ * sizeof(int));
  int*   deg_in   = (int*)alloc(N_ * sizeof(int));
  int*   deg_out  = (int*)alloc(N_ * sizeof(int));
  int*   fillc    = (int*)alloc(N_ * sizeof(int));
  float* in_norm  = (float*)alloc(N_ * sizeof(float));
  float* out_norm = (float*)alloc(N_ * sizeof(float));
  float* dvec     = (float*)alloc(P_ * sizeof(float));
  float* h        = (float*)alloc((size_t)N_ * D_ * sizeof(float));
  float* hr       = (float*)alloc((size_t)N_ * D_ * sizeof(float));
  float* z        = (float*)alloc((size_t)N_ * D_ * sizeof(float));
  float* tA       = (float*)alloc((size_t)N_ * D_ * sizeof(float));
  float* tB       = (float*)alloc((size_t)N_ * D_ * sizeof(float));

  hipMemsetAsync(deg_in, 0, N_ * sizeof(int), stream);
  hipMemsetAsync(deg_out, 0, N_ * sizeof(int), stream);
  hipMemsetAsync(fillc, 0, N_ * sizeof(int), stream);
  hipMemsetAsync(h, 0, (size_t)N_ * D_ * sizeof(float), stream);

  deg_kernel<<<(E_ + 255) / 256, 256, 0, stream>>>(src, dst, deg_out, deg_in);
  norm_kernel<<<(N_ + 255) / 256, 256, 0, stream>>>(deg_in, deg_out, in_norm, out_norm);
  scan_kernel<<<1, 1024, 0, stream>>>(deg_in, row_ptr);
  fill_kernel<<<(E_ + 255) / 256, 256, 0, stream>>>(src, dst, row_ptr, fillc, colv);
  dvec_kernel<<<(P_ + 255) / 256, 256, 0, stream>>>(dis, ti, dvec);

  const int GPRE = (N_ + 31) / 32;       // 313
  const int GGAT = (N_ + 7) / 8;         // 1250
  const int GPRD = (P_ + 15) / 16;       // 1250

  for (int t = 0; t < T_; ++t) {
    const float* xt = x + (size_t)t * N_ * XS_;
    // ---- ru gnn ----
    pre_kernel<<<GPRE, 256, 0, stream>>>(h, xt, out_norm, ru_W1, tA);
    gather_kernel<64, 0><<<GGAT, 512, 0, stream>>>(
        tA, row_ptr, colv, in_norm, out_norm, ru_W2, ru_b1, tB,
        nullptr, nullptr, nullptr, nullptr);
    gather_kernel<64, 1><<<GGAT, 512, 0, stream>>>(
        tB, row_ptr, colv, in_norm, out_norm, nullptr, ru_b2, tA,
        nullptr, nullptr, nullptr, nullptr);
    gather_kernel<128, 2><<<GGAT, 512, 0, stream>>>(
        tA, row_ptr, colv, in_norm, out_norm, ru_W3, ru_b3, nullptr,
        h, hr, nullptr, z);
    // ---- rh gnn ----
    pre_kernel<<<GPRE, 256, 0, stream>>>(hr, xt, out_norm, rh_W1, tA);
    gather_kernel<64, 0><<<GGAT, 512, 0, stream>>>(
        tA, row_ptr, colv, in_norm, out_norm, rh_W2, rh_b1, tB,
        nullptr, nullptr, nullptr, nullptr);
    gather_kernel<64, 1><<<GGAT, 512, 0, stream>>>(
        tB, row_ptr, colv, in_norm, out_norm, nullptr, rh_b2, tA,
        nullptr, nullptr, nullptr, nullptr);
    gather_kernel<64, 3><<<GGAT, 512, 0, stream>>>(
        tA, row_ptr, colv, in_norm, out_norm, rh_W3, rh_b3, nullptr,
        h, h, z, nullptr);
    // ---- prediction for this step ----
    pred_kernel<<<GPRD, 256, 0, stream>>>(h, ti, dvec, pred_W, pred_b, out, t);
  }
}